// Round 1
// baseline (134.228 us; speedup 1.0000x reference)
//
#include <hip/hip_runtime.h>

// MyConv2D: N=32, Cin=128, H=W=56, Cout=256, K=3, stride=1, pad=1, fp32.
// Strategy: preprocess W and x to fp16 in d_ws (Wt: K-loop-ordered; xt: NHWC),
// then implicit-GEMM with mfma_f32_16x16x32_f16 in the m97 128x128-tile
// structure (BK=32, 4 waves, global_load_lds width=16, linear LDS, dbuf).

typedef unsigned short u16;
typedef _Float16 f16x8 __attribute__((ext_vector_type(8)));
typedef float f32x4 __attribute__((ext_vector_type(4)));

#define NB     32
#define CIN    128
#define COUT   256
#define HW     56
#define NPIX   3136        // 56*56
#define TOTPIX (NB*NPIX)   // 100352
#define NSTEP  36          // 9 taps * (128/32) ic-blocks

__device__ __forceinline__ void gload16(const void* g, void* l) {
  __builtin_amdgcn_global_load_lds(
      (const __attribute__((address_space(1))) void*)g,
      (__attribute__((address_space(3))) void*)l, 16, 0, 0);
}

__device__ __forceinline__ u16 f2h(float f) {
  _Float16 h = (_Float16)f;
  return __builtin_bit_cast(u16, h);
}

// ---- prep_w: W[oc][ic][kh][kw] fp32 -> Wt[s][oc][icl] fp16, s = t*4 + ic/32.
// Also zeroes the 256B zero-page (block 0).
__global__ void prep_w(const float* __restrict__ W, u16* __restrict__ Wt,
                       u16* __restrict__ zp) {
  int e = blockIdx.x * 256 + threadIdx.x;     // 1152 blocks * 256 = 294912
  if (blockIdx.x == 0 && threadIdx.x < 128) zp[threadIdx.x] = 0;
  int icl = e & 31;
  int oc  = (e >> 5) & 255;
  int s   = e >> 13;                          // 0..35
  int t   = s >> 2;
  int ic  = (s & 3) * 32 + icl;
  Wt[e] = f2h(W[(oc * CIN + ic) * 9 + t]);
}

// ---- prep_x: x NCHW fp32 -> xt NHWC fp16 (LDS transpose, 64 pix x 128 ic per block)
__global__ void prep_x(const float* __restrict__ x, u16* __restrict__ xt) {
  __shared__ unsigned int tile[64 * 65];      // [pix][icpair], +1 pad
  int b = blockIdx.x;                         // 1568 = 32 * 49
  int n = b / 49;
  int hw0 = (b % 49) * 64;
  int tid = threadIdx.x;
  const float* xb = x + (size_t)n * CIN * NPIX + hw0;
  #pragma unroll
  for (int i = 0; i < 16; ++i) {
    int e = tid + i * 256;
    int icp = e >> 6;                         // 0..63 (pair of channels)
    int pix = e & 63;
    float a = xb[(size_t)(2 * icp) * NPIX + pix];
    float c = xb[(size_t)(2 * icp + 1) * NPIX + pix];
    tile[pix * 65 + icp] = (unsigned)f2h(a) | ((unsigned)f2h(c) << 16);
  }
  __syncthreads();
  u16* outb = xt + (size_t)(n * NPIX + hw0) * CIN;
  #pragma unroll
  for (int i = 0; i < 4; ++i) {
    int e = tid + i * 256;
    int pix = e >> 4;
    int q = e & 15;                           // 16B chunk within pixel's 256B
    uint4 v;
    v.x = tile[pix * 65 + q * 4 + 0];
    v.y = tile[pix * 65 + q * 4 + 1];
    v.z = tile[pix * 65 + q * 4 + 2];
    v.w = tile[pix * 65 + q * 4 + 3];
    *(uint4*)(outb + (size_t)pix * CIN + q * 8) = v;
  }
}

// ---- main: implicit-GEMM conv, 128(oc) x 128(pix) tile, BK=32, 4 waves.
__global__ __launch_bounds__(256) void conv_mfma(
    const u16* __restrict__ Wt, const u16* __restrict__ xt,
    const float* __restrict__ bias, float* __restrict__ out,
    const u16* __restrict__ zp) {
  __shared__ __align__(16) u16 sA[2][4096];   // [oc 128][k 32] fp16, 8KB each
  __shared__ __align__(16) u16 sB[2][4096];   // [pix 128][k 32] fp16

  int tid  = threadIdx.x;
  int lane = tid & 63;
  int wv   = tid >> 6;
  int bid  = blockIdx.x;
  int octile = bid & 1;                       // 0..1
  int ptile  = bid >> 1;                      // 0..783

  // Staging slots: each thread owns two 16B slots per tile: s0, s0+64.
  int s0 = wv * 128 + lane;
  int s1 = s0 + 64;
  // B slots -> (pixel-in-tile, k-quarter)
  int pp0 = s0 >> 2, q0 = s0 & 3;
  int pp1 = s1 >> 2, q1 = s1 & 3;
  int p0g = ptile * 128 + pp0, p1g = ptile * 128 + pp1;
  int n0 = p0g / NPIX, r0 = p0g % NPIX, h0 = r0 / HW, w0 = r0 % HW;
  int n1 = p1g / NPIX, r1 = p1g % NPIX, h1 = r1 / HW, w1 = r1 % HW;
  const char* xb0 = (const char*)xt + (size_t)n0 * NPIX * 256 + q0 * 16;
  const char* xb1 = (const char*)xt + (size_t)n1 * NPIX * 256 + q1 * 16;
  // A slots -> (oc-in-tile, k-quarter); same slot decomposition
  const char* wb0 = (const char*)Wt + ((octile * 128 + pp0) * 32 + q0 * 8) * 2;
  const char* wb1 = (const char*)Wt + ((octile * 128 + pp1) * 32 + q1 * 8) * 2;

  // Fragment LDS offsets (u16 units)
  int wm = wv >> 1, wn = wv & 1;
  int l15 = lane & 15, lg = lane >> 4;
  int aidx[4], bidx[4];
  #pragma unroll
  for (int i = 0; i < 4; ++i) {
    aidx[i] = (wm * 64 + i * 16 + l15) * 32 + lg * 8;
    bidx[i] = (wn * 64 + i * 16 + l15) * 32 + lg * 8;
  }

  f32x4 acc[4][4] = {};

  auto stage = [&](int s, int buf) {
    int t = s >> 2, icb = s & 3;
    int dh = t / 3 - 1, dw = t % 3 - 1;
    // A: weights, linear in s
    gload16(wb0 + (size_t)s * 16384, &sA[buf][(wv * 2 + 0) * 512]);
    gload16(wb1 + (size_t)s * 16384, &sA[buf][(wv * 2 + 1) * 512]);
    // B: im2col on the fly (zero-page for OOB taps)
    int ih0 = h0 + dh, iw0 = w0 + dw;
    int ih1 = h1 + dh, iw1 = w1 + dw;
    const void* g0 = ((unsigned)ih0 < HW && (unsigned)iw0 < HW)
                         ? (const void*)(xb0 + (ih0 * HW + iw0) * 256 + icb * 64)
                         : (const void*)zp;
    const void* g1 = ((unsigned)ih1 < HW && (unsigned)iw1 < HW)
                         ? (const void*)(xb1 + (ih1 * HW + iw1) * 256 + icb * 64)
                         : (const void*)zp;
    gload16(g0, &sB[buf][(wv * 2 + 0) * 512]);
    gload16(g1, &sB[buf][(wv * 2 + 1) * 512]);
  };

  stage(0, 0);
  __syncthreads();
  #pragma unroll 2
  for (int s = 0; s < NSTEP; ++s) {
    if (s < NSTEP - 1) stage(s + 1, (s + 1) & 1);
    int cur = s & 1;
    f16x8 af[4], bf[4];
    #pragma unroll
    for (int i = 0; i < 4; ++i) af[i] = *(const f16x8*)&sA[cur][aidx[i]];
    #pragma unroll
    for (int i = 0; i < 4; ++i) bf[i] = *(const f16x8*)&sB[cur][bidx[i]];
    #pragma unroll
    for (int mi = 0; mi < 4; ++mi)
      #pragma unroll
      for (int nf = 0; nf < 4; ++nf)
        acc[mi][nf] = __builtin_amdgcn_mfma_f32_16x16x32_f16(
            af[mi], bf[nf], acc[mi][nf], 0, 0, 0);
    __syncthreads();
  }

  // Epilogue: C/D layout: row(M=oc) = (lane>>4)*4 + reg, col(N=pix) = lane&15
  int pn[4], phw[4];
  #pragma unroll
  for (int nf = 0; nf < 4; ++nf) {
    int p = ptile * 128 + wn * 64 + nf * 16 + l15;
    pn[nf] = p / NPIX;
    phw[nf] = p % NPIX;
  }
  #pragma unroll
  for (int mi = 0; mi < 4; ++mi) {
    int ocb = octile * 128 + wm * 64 + mi * 16 + lg * 4;
    #pragma unroll
    for (int r = 0; r < 4; ++r) {
      float bv = bias[ocb + r];
      #pragma unroll
      for (int nf = 0; nf < 4; ++nf)
        out[(size_t)(pn[nf] * COUT + ocb + r) * NPIX + phw[nf]] =
            acc[mi][nf][r] + bv;
    }
  }
}

// ---- fallback (only if ws too small): naive fp32 direct conv
__global__ void conv_naive(const float* __restrict__ x, const float* __restrict__ W,
                           const float* __restrict__ b, float* __restrict__ out) {
  int idx = blockIdx.x * 256 + threadIdx.x;   // 100352 blocks cover exactly
  int hw = idx % NPIX;
  int tmp = idx / NPIX;
  int oc = tmp % COUT;
  int n = tmp / COUT;
  int h = hw / HW, w = hw % HW;
  float acc = b[oc];
  for (int ic = 0; ic < CIN; ++ic) {
    const float* xr = x + (size_t)(n * CIN + ic) * NPIX;
    const float* wr = W + (size_t)(oc * CIN + ic) * 9;
    #pragma unroll
    for (int kh = 0; kh < 3; ++kh) {
      int ih = h + kh - 1;
      if ((unsigned)ih >= HW) continue;
      #pragma unroll
      for (int kw = 0; kw < 3; ++kw) {
        int iw = w + kw - 1;
        if ((unsigned)iw >= HW) continue;
        acc += xr[ih * HW + iw] * wr[kh * 3 + kw];
      }
    }
  }
  out[idx] = acc;
}

extern "C" void kernel_launch(void* const* d_in, const int* in_sizes, int n_in,
                              void* d_out, int out_size, void* d_ws, size_t ws_size,
                              hipStream_t stream) {
  const float* x = (const float*)d_in[0];
  const float* W = (const float*)d_in[1];
  const float* b = (const float*)d_in[2];
  float* out = (float*)d_out;

  const size_t ZP_OFF = 0;                    // 256 B zero page
  const size_t WT_OFF = 256;                  // 36*256*32*2 = 589824 B
  const size_t XT_OFF = 256 + 589824;         // 590080 (16B aligned)
  const size_t NEED = XT_OFF + (size_t)TOTPIX * CIN * 2;  // ~26.3 MB

  if (ws_size < NEED) {
    conv_naive<<<TOTPIX * COUT / 256 / 1, 256, 0, stream>>>(x, W, b, out);
    return;
  }
  char* ws = (char*)d_ws;
  u16* zp = (u16*)(ws + ZP_OFF);
  u16* Wt = (u16*)(ws + WT_OFF);
  u16* xt = (u16*)(ws + XT_OFF);

  prep_w<<<1152, 256, 0, stream>>>(W, Wt, zp);
  prep_x<<<1568, 256, 0, stream>>>(x, xt);
  conv_mfma<<<1568, 256, 0, stream>>>(Wt, xt, b, out, zp);
}

// Round 2
// 131.486 us; speedup vs baseline: 1.0209x; 1.0209x over previous
//
#include <hip/hip_runtime.h>

// MyConv2D: N=32, Cin=128, H=W=56, Cout=256, K=3, stride=1, pad=1, fp32.
// R2: implicit-GEMM fp16 MFMA, 256(oc)x128(pix) tile, BK=32, 8 waves,
// triple-buffered LDS with counted s_waitcnt vmcnt(6) pipeline (T3+T4),
// conflict-free [k-quarter][row][16B] LDS layout (no XOR needed since we
// control both prep_w's layout and the linear global_load_lds granule order).

typedef unsigned short u16;
typedef _Float16 f16x8 __attribute__((ext_vector_type(8)));
typedef float f32x4 __attribute__((ext_vector_type(4)));

#define NB     32
#define CIN    128
#define COUT   256
#define HW     56
#define NPIX   3136        // 56*56
#define TOTPIX (NB*NPIX)   // 100352
#define NSTEP  36          // 9 taps * (128/32) ic-blocks

#define WAITVM6  asm volatile("s_waitcnt vmcnt(6)" ::: "memory")
#define WAITVM3  asm volatile("s_waitcnt vmcnt(3)" ::: "memory")
#define WAITVM0  asm volatile("s_waitcnt vmcnt(0)" ::: "memory")
#define WAITLGKM asm volatile("s_waitcnt lgkmcnt(0)" ::: "memory")
#define BAR      __builtin_amdgcn_s_barrier()

__device__ __forceinline__ void gload16(const void* g, void* l) {
  __builtin_amdgcn_global_load_lds(
      (const __attribute__((address_space(1))) void*)g,
      (__attribute__((address_space(3))) void*)l, 16, 0, 0);
}

__device__ __forceinline__ u16 f2h(float f) {
  _Float16 h = (_Float16)f;
  return __builtin_bit_cast(u16, h);
}

// ---- prep_w: W[oc][ic][kh][kw] fp32 -> Wt[s][q][oc][8] fp16.
// s = tap*4 + ic/32 (K-step), q = k-quarter within step, 8 = ic within quarter.
// This matches the conv kernel's linear staging granule order exactly.
// Also zeroes the 256B zero-page (block 0).
__global__ void prep_w(const float* __restrict__ W, u16* __restrict__ Wt,
                       u16* __restrict__ zp) {
  int e = blockIdx.x * 256 + threadIdx.x;     // 1152 blocks * 256 = 294912
  if (blockIdx.x == 0 && threadIdx.x < 128) zp[threadIdx.x] = 0;
  int j  = e & 7;
  int oc = (e >> 3) & 255;
  int q  = (e >> 11) & 3;
  int s  = e >> 13;                           // 0..35
  int ic = (s & 3) * 32 + q * 8 + j;
  Wt[e] = f2h(W[(oc * CIN + ic) * 9 + (s >> 2)]);
}

// ---- prep_x: x NCHW fp32 -> xt NHWC fp16 (LDS transpose, 64 pix x 128 ic per block)
__global__ void prep_x(const float* __restrict__ x, u16* __restrict__ xt) {
  __shared__ unsigned int tile[64 * 65];      // [pix][icpair], +1 pad
  int b = blockIdx.x;                         // 1568 = 32 * 49
  int n = b / 49;
  int hw0 = (b % 49) * 64;
  int tid = threadIdx.x;
  const float* xb = x + (size_t)n * CIN * NPIX + hw0;
  #pragma unroll
  for (int i = 0; i < 16; ++i) {
    int e = tid + i * 256;
    int icp = e >> 6;                         // 0..63 (pair of channels)
    int pix = e & 63;
    float a = xb[(size_t)(2 * icp) * NPIX + pix];
    float c = xb[(size_t)(2 * icp + 1) * NPIX + pix];
    tile[pix * 65 + icp] = (unsigned)f2h(a) | ((unsigned)f2h(c) << 16);
  }
  __syncthreads();
  u16* outb = xt + (size_t)(n * NPIX + hw0) * CIN;
  #pragma unroll
  for (int i = 0; i < 4; ++i) {
    int e = tid + i * 256;
    int pix = e >> 4;
    int q = e & 15;                           // 16B chunk within pixel's 256B
    uint4 v;
    v.x = tile[pix * 65 + q * 4 + 0];
    v.y = tile[pix * 65 + q * 4 + 1];
    v.z = tile[pix * 65 + q * 4 + 2];
    v.w = tile[pix * 65 + q * 4 + 3];
    *(uint4*)(outb + (size_t)pix * CIN + q * 8) = v;
  }
}

// ---- main: implicit-GEMM conv, 256(oc) x 128(pix) tile, BK=32, 8 waves,
// 3 LDS buffers, prefetch depth 2, counted vmcnt.
__global__ __launch_bounds__(512) void conv_mfma(
    const u16* __restrict__ Wt, const u16* __restrict__ xt,
    const float* __restrict__ bias, float* __restrict__ out,
    const u16* __restrict__ zp) {
  // Layout: [q(k-quarter,4)][row][16B granule] -> fragment ds_read_b128 has
  // 16 consecutive rows per lane-quarter = sequential banks, conflict-free.
  __shared__ __align__(16) u16 sA[3][8192];   // 16KB each: 4 q * 256 oc * 8
  __shared__ __align__(16) u16 sB[3][4096];   // 8KB each: 4 q * 128 pix * 8

  int tid  = threadIdx.x;                     // 0..511
  int lane = tid & 63;
  int wv   = tid >> 6;                        // 0..7
  int ptile = blockIdx.x;                     // 0..783

  // B staging: thread t owns granule t: q = t>>7, pix = t&127.
  int bq   = tid >> 7;
  int bpix = tid & 127;
  int pg = ptile * 128 + bpix;
  int n = pg / NPIX, rr = pg % NPIX, h = rr / HW, w = rr % HW;
  const char* xbase = (const char*)xt + (size_t)n * NPIX * 256
                    + (h * HW + w) * 256 + bq * 16;
  // A staging: thread t owns granules t (q 0..1) and t+512 (q 2..3);
  // Wt layout matches linearly, so src = Wt + s*16384 + granule*16.
  const char* wbase = (const char*)Wt + tid * 16;

  int wm = wv >> 1, wn = wv & 1;              // wave tile: 64(oc) x 64(pix)
  int l15 = lane & 15, lg = lane >> 4;
  int aoff[4], boff[4];
  #pragma unroll
  for (int i = 0; i < 4; ++i) {
    aoff[i] = (lg * 256 + wm * 64 + i * 16 + l15) * 8;
    boff[i] = (lg * 128 + wn * 64 + i * 16 + l15) * 8;
  }

  f32x4 acc[4][4] = {};

  auto stage = [&](int s2, u16* bufA, u16* bufB) {
    // A: 2 granules, constant 8KB apart
    gload16(wbase + (size_t)s2 * 16384, &bufA[tid * 8]);
    gload16(wbase + (size_t)s2 * 16384 + 8192, &bufA[tid * 8 + 4096]);
    // B: im2col on the fly (zero-page for OOB taps)
    int t9 = s2 >> 2, icb = s2 & 3;
    int t3 = t9 / 3;
    int dh = t3 - 1, dw = (t9 - t3 * 3) - 1;
    int ih = h + dh, iw = w + dw;
    const void* g = ((unsigned)ih < HW && (unsigned)iw < HW)
        ? (const void*)(xbase + ((dh * HW + dw) * 256 + icb * 64))
        : (const void*)zp;
    gload16(g, &bufB[tid * 8]);
  };

  auto compute = [&](const u16* bufA, const u16* bufB) {
    f16x8 af[4], bf[4];
    #pragma unroll
    for (int i = 0; i < 4; ++i) af[i] = *(const f16x8*)&bufA[aoff[i]];
    #pragma unroll
    for (int i = 0; i < 4; ++i) bf[i] = *(const f16x8*)&bufB[boff[i]];
    #pragma unroll
    for (int mi = 0; mi < 4; ++mi)
      #pragma unroll
      for (int nf = 0; nf < 4; ++nf)
        acc[mi][nf] = __builtin_amdgcn_mfma_f32_16x16x32_f16(
            af[mi], bf[nf], acc[mi][nf], 0, 0, 0);
  };

  // Prologue: 2 stages in flight (6 loads/thread).
  stage(0, sA[0], sB[0]);
  stage(1, sA[1], sB[1]);
  // Steady state: issue stage(s+2), wait vmcnt(6) -> stage(s) landed,
  // barrier, compute(s), lgkmcnt(0), barrier. Loads never drained to 0.
  for (int s = 0; s < 33; s += 3) {
    stage(s + 2, sA[2], sB[2]); WAITVM6; BAR; compute(sA[0], sB[0]); WAITLGKM; BAR;
    stage(s + 3, sA[0], sB[0]); WAITVM6; BAR; compute(sA[1], sB[1]); WAITLGKM; BAR;
    stage(s + 4, sA[1], sB[1]); WAITVM6; BAR; compute(sA[2], sB[2]); WAITLGKM; BAR;
  }
  // Peeled tail: steps 33, 34, 35 (stage(35) is the last issue).
  stage(35, sA[2], sB[2]); WAITVM6; BAR; compute(sA[0], sB[0]); WAITLGKM; BAR;
  WAITVM3; BAR; compute(sA[1], sB[1]); WAITLGKM; BAR;
  WAITVM0; BAR; compute(sA[2], sB[2]);

  // Epilogue: C/D layout: row(M=oc) = (lane>>4)*4 + reg, col(N=pix) = lane&15
  int pn[4], phw[4];
  #pragma unroll
  for (int nf = 0; nf < 4; ++nf) {
    int p = ptile * 128 + wn * 64 + nf * 16 + l15;
    pn[nf] = p / NPIX;
    phw[nf] = p % NPIX;
  }
  #pragma unroll
  for (int mi = 0; mi < 4; ++mi) {
    int ocb = wm * 64 + mi * 16 + lg * 4;
    #pragma unroll
    for (int r = 0; r < 4; ++r) {
      float bv = bias[ocb + r];
      #pragma unroll
      for (int nf = 0; nf < 4; ++nf)
        out[(size_t)(pn[nf] * COUT + ocb + r) * NPIX + phw[nf]] =
            acc[mi][nf][r] + bv;
    }
  }
}

// ---- fallback (only if ws too small): naive fp32 direct conv
__global__ void conv_naive(const float* __restrict__ x, const float* __restrict__ W,
                           const float* __restrict__ b, float* __restrict__ out) {
  int idx = blockIdx.x * 256 + threadIdx.x;
  int hw = idx % NPIX;
  int tmp = idx / NPIX;
  int oc = tmp % COUT;
  int n = tmp / COUT;
  int h = hw / HW, w = hw % HW;
  float acc = b[oc];
  for (int ic = 0; ic < CIN; ++ic) {
    const float* xr = x + (size_t)(n * CIN + ic) * NPIX;
    const float* wr = W + (size_t)(oc * CIN + ic) * 9;
    #pragma unroll
    for (int kh = 0; kh < 3; ++kh) {
      int ih = h + kh - 1;
      if ((unsigned)ih >= HW) continue;
      #pragma unroll
      for (int kw = 0; kw < 3; ++kw) {
        int iw = w + kw - 1;
        if ((unsigned)iw >= HW) continue;
        acc += xr[ih * HW + iw] * wr[kh * 3 + kw];
      }
    }
  }
  out[idx] = acc;
}

extern "C" void kernel_launch(void* const* d_in, const int* in_sizes, int n_in,
                              void* d_out, int out_size, void* d_ws, size_t ws_size,
                              hipStream_t stream) {
  const float* x = (const float*)d_in[0];
  const float* W = (const float*)d_in[1];
  const float* b = (const float*)d_in[2];
  float* out = (float*)d_out;

  const size_t ZP_OFF = 0;                    // 256 B zero page
  const size_t WT_OFF = 256;                  // 36*4*256*8*2 = 589824 B
  const size_t XT_OFF = 256 + 589824;         // 590080 (16B aligned)
  const size_t NEED = XT_OFF + (size_t)TOTPIX * CIN * 2;  // ~26.3 MB

  if (ws_size < NEED) {
    conv_naive<<<TOTPIX * COUT / 256, 256, 0, stream>>>(x, W, b, out);
    return;
  }
  char* ws = (char*)d_ws;
  u16* zp = (u16*)(ws + ZP_OFF);
  u16* Wt = (u16*)(ws + WT_OFF);
  u16* xt = (u16*)(ws + XT_OFF);

  prep_w<<<1152, 256, 0, stream>>>(W, Wt, zp);
  prep_x<<<1568, 256, 0, stream>>>(x, xt);
  conv_mfma<<<784, 512, 0, stream>>>(Wt, xt, b, out, zp);
}

// Round 4
// 101.725 us; speedup vs baseline: 1.3195x; 1.2926x over previous
//
#include <hip/hip_runtime.h>

// MyConv2D: N=32, Cin=128, H=W=56, Cout=256, K=3, stride=1, pad=1, fp32.
// R4 == R3 resubmit (R3 bench failed on container infra, kernel never ran).
// m201-style 8-phase schedule. 256(oc)x256(pix) tile, BK=64, 8 waves
// (2M x 4N, per-wave 128x64), 128KB LDS double-buffered, 4 quadrant-phases
// per K-tile, counted vmcnt(2) once per K-tile, setprio around MFMA clusters,
// conflict-free [k8][row][16B] LDS layout, linear global_load_lds staging,
// XCD-aware block swizzle (392 % 8 == 0).

typedef unsigned short u16;
typedef _Float16 f16x8 __attribute__((ext_vector_type(8)));
typedef float f32x4 __attribute__((ext_vector_type(4)));

#define CIN    128
#define COUT   256
#define HW     56
#define NPIX   3136        // 56*56
#define TOTPIX 100352      // 32*3136
#define NKT    18          // K-tiles of 64 ic: 9 taps * 2 ic-halves

#define WAITVM2 asm volatile("s_waitcnt vmcnt(2)" ::: "memory")
#define WAITVM0 asm volatile("s_waitcnt vmcnt(0)" ::: "memory")
#define BARRIER asm volatile("s_barrier" ::: "memory")

__device__ __forceinline__ void gload16(const void* g, void* l) {
  __builtin_amdgcn_global_load_lds(
      (const __attribute__((address_space(1))) void*)g,
      (__attribute__((address_space(3))) void*)l, 16, 0, 0);
}

__device__ __forceinline__ u16 f2h(float f) {
  _Float16 h = (_Float16)f;
  return __builtin_bit_cast(u16, h);
}

// ---- prep_w: W[oc][ic][3][3] fp32 -> Wt fp16, element e decomposed as
// j=e&7 (ic low), ocl=(e>>3)&127, k8=(e>>10)&7, half=(e>>13)&1, t=e>>14.
// oc = half*128+ocl; ic = (t&1)*64 + k8*8 + j; tap = t>>1.
// This is exactly the conv kernel's linear staging granule order.
__global__ void prep_w(const float* __restrict__ W, u16* __restrict__ Wt,
                       u16* __restrict__ zp) {
  int e = blockIdx.x * 256 + threadIdx.x;     // 1152 blocks * 256 = 294912
  if (blockIdx.x == 0 && threadIdx.x < 128) zp[threadIdx.x] = 0;
  int j    = e & 7;
  int ocl  = (e >> 3) & 127;
  int k8   = (e >> 10) & 7;
  int half = (e >> 13) & 1;
  int t    = e >> 14;                         // 0..17
  int oc = half * 128 + ocl;
  int ic = (t & 1) * 64 + k8 * 8 + j;
  Wt[e] = f2h(W[(oc * CIN + ic) * 9 + (t >> 1)]);
}

// ---- prep_x: x NCHW fp32 -> xt NHWC fp16 (LDS transpose, 64 pix x 128 ic)
__global__ void prep_x(const float* __restrict__ x, u16* __restrict__ xt) {
  __shared__ unsigned int tile[64 * 65];
  int b = blockIdx.x;                         // 1568 = 32 * 49
  int n = b / 49;
  int hw0 = (b % 49) * 64;
  int tid = threadIdx.x;
  const float* xb = x + (size_t)n * CIN * NPIX + hw0;
  #pragma unroll
  for (int i = 0; i < 16; ++i) {
    int e = tid + i * 256;
    int icp = e >> 6;
    int pix = e & 63;
    float a = xb[(size_t)(2 * icp) * NPIX + pix];
    float c = xb[(size_t)(2 * icp + 1) * NPIX + pix];
    tile[pix * 65 + icp] = (unsigned)f2h(a) | ((unsigned)f2h(c) << 16);
  }
  __syncthreads();
  u16* outb = xt + (size_t)(n * NPIX + hw0) * CIN;
  #pragma unroll
  for (int i = 0; i < 4; ++i) {
    int e = tid + i * 256;
    int pix = e >> 4;
    int q = e & 15;
    uint4 v;
    v.x = tile[pix * 65 + q * 4 + 0];
    v.y = tile[pix * 65 + q * 4 + 1];
    v.z = tile[pix * 65 + q * 4 + 2];
    v.w = tile[pix * 65 + q * 4 + 3];
    *(uint4*)(outb + (size_t)pix * CIN + q * 8) = v;
  }
}

// MFMA quadrant: 4 m-frags x 2 n-frags x 2 k-steps = 16 MFMA. MH/NH literal.
#define QUAD(MH, NH)                                                          \
  do {                                                                        \
    __builtin_amdgcn_s_setprio(1);                                            \
    _Pragma("unroll") for (int mq = 0; mq < 4; ++mq)                          \
    _Pragma("unroll") for (int nf = 0; nf < 2; ++nf)                          \
    _Pragma("unroll") for (int kk = 0; kk < 2; ++kk)                          \
      acc[(MH)*4 + mq][(NH)*2 + nf] =                                         \
          __builtin_amdgcn_mfma_f32_16x16x32_f16(                             \
              af[mq][kk], bf[(NH)][nf][kk], acc[(MH)*4 + mq][(NH)*2 + nf],    \
              0, 0, 0);                                                       \
    __builtin_amdgcn_s_setprio(0);                                            \
  } while (0)

#define READB(BUFO, NH)                                                       \
  do {                                                                        \
    _Pragma("unroll") for (int nf = 0; nf < 2; ++nf)                          \
    _Pragma("unroll") for (int kk = 0; kk < 2; ++kk)                          \
      bf[(NH)][nf][kk] = *(const f16x8*)&lds[(BUFO) + 16384 + bhalf * 8192 +  \
          ((kk * 4 + lg) * 128 + bpl + (NH)*32 + nf * 16) * 8];               \
  } while (0)

__global__ __launch_bounds__(512, 2) void conv_mfma(
    const u16* __restrict__ Wt, const u16* __restrict__ xt,
    const float* __restrict__ bias, float* __restrict__ out,
    const u16* __restrict__ zp) {
  // LDS: [buf 2][ A: [half][k8][ocl][8]  32KB | B: [half][k8][pixl][8] 32KB ]
  __shared__ __align__(16) u16 lds[65536];    // 128 KB

  int tid  = threadIdx.x;                     // 0..511
  int lane = tid & 63;
  int wv   = tid >> 6;                        // 0..7
  int bid  = blockIdx.x;                      // 0..391
  int ptile = (bid & 7) * 49 + (bid >> 3);    // XCD swizzle (392 = 8*49)

  int wm = wv >> 2, wn = wv & 3;              // 2M x 4N waves
  int l15 = lane & 15, lg = lane >> 4;
  int bhalf = wn >> 1;
  int bpl = (wn & 1) * 64 + l15;

  // Staging geometry: thread owns pixel-row pixl for B, linear granules for A.
  int pixl = tid & 127, tph = tid >> 7;
  int p0 = ptile * 256 + pixl, p1 = p0 + 128;
  int n0 = p0 / NPIX, r0 = p0 % NPIX, y0 = r0 / HW, x0 = r0 % HW;
  int n1 = p1 / NPIX, r1 = p1 % NPIX, y1 = r1 / HW, x1 = r1 % HW;
  const char* xb0 = (const char*)xt + ((size_t)n0 * NPIX + r0) * 256;
  const char* xb1 = (const char*)xt + ((size_t)n1 * NPIX + r1) * 256;
  const char* wsrc = (const char*)Wt + tid * 16;
  const char* zpc = (const char*)zp;

  auto stageA = [&](int tn, int h) {
    const char* src = wsrc + (size_t)(tn * 2048 + h * 1024) * 16;
    u16* dst = &lds[(tn & 1) * 32768 + h * 8192 + tid * 8];
    gload16(src, dst);
    gload16(src + 8192, dst + 4096);          // pass 1: +512 granules
  };
  auto stageB = [&](int tn, int h, const char* src) {
    u16* dst = &lds[(tn & 1) * 32768 + 16384 + h * 8192 + tid * 8];
    gload16(src, dst);
    gload16(src + 64, dst + 4096);            // pass 1: k8 += 4 -> +64 B
  };
  // B global source for (tap, icb, half): shifted pixel or zero-page.
  auto bsrc = [&](int tap, int icb, int h) -> const char* {
    int t3 = tap / 3;
    int dh = t3 - 1, dw = (tap - t3 * 3) - 1;
    int ih = (h ? y1 : y0) + dh, iw = (h ? x1 : x0) + dw;
    const char* xb = h ? xb1 : xb0;
    return ((unsigned)ih < HW && (unsigned)iw < HW)
        ? xb + (dh * HW + dw) * 256 + icb * 128 + tph * 16
        : zpc + tph * 16;
  };

  f32x4 acc[8][4] = {};
  f16x8 af[4][2], bf[2][2][2];

  auto readA = [&](int bufo, int mh) {
    #pragma unroll
    for (int mq = 0; mq < 4; ++mq)
      #pragma unroll
      for (int kk = 0; kk < 2; ++kk)
        af[mq][kk] = *(const f16x8*)&lds[bufo + wm * 8192 +
            ((kk * 4 + lg) * 128 + mh * 64 + mq * 16 + l15) * 8];
  };

  // Prologue: stage K-tile 0 (8 loads/thread).
  stageA(0, 0); stageB(0, 0, bsrc(0, 0, 0));
  stageA(0, 1); stageB(0, 1, bsrc(0, 0, 1));

  for (int t = 0; t < NKT; ++t) {
    int bufo = (t & 1) * 32768;
    int tn = t + 1;
    const char *sb0 = zpc, *sb1 = zpc;
    if (tn < NKT) { sb0 = bsrc(tn >> 1, tn & 1, 0); sb1 = bsrc(tn >> 1, tn & 1, 1); }
    // ---- phase 0: quadrant (m0,n0); stage A0(t+1); the K-tile's only vmcnt.
    if (tn < NKT) { stageA(tn, 0); WAITVM2; } else { WAITVM0; }
    BARRIER;
    readA(bufo, 0); READB(bufo, 0);
    QUAD(0, 0);
    BARRIER;
    // ---- phase 1: quadrant (m0,n1); stage B0(t+1).
    READB(bufo, 1);
    if (tn < NKT) stageB(tn, 0, sb0);
    BARRIER;
    QUAD(0, 1);
    BARRIER;
    // ---- phase 2: quadrant (m1,n1); stage A1(t+1).
    readA(bufo, 1);
    if (tn < NKT) stageA(tn, 1);
    BARRIER;
    QUAD(1, 1);
    BARRIER;
    // ---- phase 3: quadrant (m1,n0); stage B1(t+1). B n0 frags still live.
    if (tn < NKT) stageB(tn, 1, sb1);
    BARRIER;
    QUAD(1, 0);
    BARRIER;
  }

  // Epilogue. C/D: row(oc) = lg*4 + reg (+ frag offsets), col(pix) = l15.
  #pragma unroll
  for (int nf4 = 0; nf4 < 4; ++nf4) {
    int p = ptile * 256 + wn * 64 + nf4 * 16 + l15;
    int n = p / NPIX, hw = p % NPIX;
    float* ob = out + (size_t)n * COUT * NPIX + hw;
    #pragma unroll
    for (int mi = 0; mi < 8; ++mi) {
      int oc = wm * 128 + mi * 16 + lg * 4;
      f32x4 bv = *(const f32x4*)&bias[oc];
      #pragma unroll
      for (int r = 0; r < 4; ++r)
        ob[(size_t)(oc + r) * NPIX] = acc[mi][nf4][r] + bv[r];
    }
  }
}

// ---- fallback (only if ws too small): naive fp32 direct conv
__global__ void conv_naive(const float* __restrict__ x, const float* __restrict__ W,
                           const float* __restrict__ b, float* __restrict__ out) {
  int idx = blockIdx.x * 256 + threadIdx.x;
  int hw = idx % NPIX;
  int tmp = idx / NPIX;
  int oc = tmp % COUT;
  int n = tmp / COUT;
  int h = hw / HW, w = hw % HW;
  float acc = b[oc];
  for (int ic = 0; ic < CIN; ++ic) {
    const float* xr = x + (size_t)(n * CIN + ic) * NPIX;
    const float* wr = W + (size_t)(oc * CIN + ic) * 9;
    #pragma unroll
    for (int kh = 0; kh < 3; ++kh) {
      int ih = h + kh - 1;
      if ((unsigned)ih >= HW) continue;
      #pragma unroll
      for (int kw = 0; kw < 3; ++kw) {
        int iw = w + kw - 1;
        if ((unsigned)iw >= HW) continue;
        acc += xr[ih * HW + iw] * wr[kh * 3 + kw];
      }
    }
  }
  out[idx] = acc;
}

extern "C" void kernel_launch(void* const* d_in, const int* in_sizes, int n_in,
                              void* d_out, int out_size, void* d_ws, size_t ws_size,
                              hipStream_t stream) {
  const float* x = (const float*)d_in[0];
  const float* W = (const float*)d_in[1];
  const float* b = (const float*)d_in[2];
  float* out = (float*)d_out;

  const size_t ZP_OFF = 0;                    // 256 B zero page
  const size_t WT_OFF = 256;                  // 294912 * 2 = 589824 B
  const size_t XT_OFF = 256 + 589824;
  const size_t NEED = XT_OFF + (size_t)TOTPIX * CIN * 2;  // ~26.3 MB

  if (ws_size < NEED) {
    conv_naive<<<TOTPIX * COUT / 256, 256, 0, stream>>>(x, W, b, out);
    return;
  }
  char* ws = (char*)d_ws;
  u16* zp = (u16*)(ws + ZP_OFF);
  u16* Wt = (u16*)(ws + WT_OFF);
  u16* xt = (u16*)(ws + XT_OFF);

  prep_w<<<1152, 256, 0, stream>>>(W, Wt, zp);
  prep_x<<<1568, 256, 0, stream>>>(x, xt);
  conv_mfma<<<392, 512, 0, stream>>>(Wt, xt, b, out, zp);
}

// Round 5
// 96.158 us; speedup vs baseline: 1.3959x; 1.0579x over previous
//
#include <hip/hip_runtime.h>

// MyConv2D: N=32, Cin=128, H=W=56, Cout=256, K=3, stride=1, pad=1, fp32.
// R5: R4's 8-phase 256x256 schedule + COALESCED B staging.
// Key change: xt layout [n][g=ic/8][pix][8ic] so stageB's 64 lanes read
// contiguous 1KB per global_load_lds (R4 had 256B-stride scatter -> 8x L2
// request amplification, the all-pipes-idle stall). LDS layouts unchanged
// (linear granule dst, caveat #21). Epilogue reordered for write-combining.

typedef unsigned short u16;
typedef _Float16 f16x8 __attribute__((ext_vector_type(8)));
typedef float f32x4 __attribute__((ext_vector_type(4)));

#define CIN    128
#define COUT   256
#define HW     56
#define NPIX   3136        // 56*56
#define TOTPIX 100352      // 32*3136
#define NKT    18          // K-tiles of 64 ic: 9 taps * 2 ic-halves

#define WAITVM2 asm volatile("s_waitcnt vmcnt(2)" ::: "memory")
#define WAITVM0 asm volatile("s_waitcnt vmcnt(0)" ::: "memory")
#define BARRIER asm volatile("s_barrier" ::: "memory")

__device__ __forceinline__ void gload16(const void* g, void* l) {
  __builtin_amdgcn_global_load_lds(
      (const __attribute__((address_space(1))) void*)g,
      (__attribute__((address_space(3))) void*)l, 16, 0, 0);
}

__device__ __forceinline__ u16 f2h(float f) {
  _Float16 h = (_Float16)f;
  return __builtin_bit_cast(u16, h);
}

// ---- prep_w: W[oc][ic][3][3] fp32 -> Wt fp16 (unchanged from R4).
// e: j=e&7, ocl=(e>>3)&127, k8=(e>>10)&7, half=(e>>13)&1, t=e>>14.
// oc = half*128+ocl; ic = (t&1)*64 + k8*8 + j; tap = t>>1.
__global__ void prep_w(const float* __restrict__ W, u16* __restrict__ Wt,
                       u16* __restrict__ zp) {
  int e = blockIdx.x * 256 + threadIdx.x;     // 1152 * 256 = 294912
  if (blockIdx.x == 0 && threadIdx.x < 128) zp[threadIdx.x] = 0;
  int j    = e & 7;
  int ocl  = (e >> 3) & 127;
  int k8   = (e >> 10) & 7;
  int half = (e >> 13) & 1;
  int t    = e >> 14;                         // 0..17
  int oc = half * 128 + ocl;
  int ic = (t & 1) * 64 + k8 * 8 + j;
  Wt[e] = f2h(W[(oc * CIN + ic) * 9 + (t >> 1)]);
}

// ---- prep_x: x NCHW fp32 -> xt [n][g=ic/8][pix][8ic] fp16 (16B granules).
// LDS transpose of 64 pix x 128 ic per block; output writes are 1KB
// contiguous per quarter-wave (consecutive lanes -> consecutive pix).
__global__ void prep_x(const float* __restrict__ x, u16* __restrict__ xt) {
  __shared__ unsigned int tile[64 * 65];      // [pix][icpair], +1 pad
  int b = blockIdx.x;                         // 1568 = 32 * 49
  int n = b / 49;
  int hw0 = (b % 49) * 64;
  int tid = threadIdx.x;
  const float* xb = x + (size_t)n * CIN * NPIX + hw0;
  #pragma unroll
  for (int i = 0; i < 16; ++i) {
    int e = tid + i * 256;
    int icp = e >> 6;                         // 0..63 (pair of channels)
    int pix = e & 63;
    float a = xb[(size_t)(2 * icp) * NPIX + pix];
    float c = xb[(size_t)(2 * icp + 1) * NPIX + pix];
    tile[pix * 65 + icp] = (unsigned)f2h(a) | ((unsigned)f2h(c) << 16);
  }
  __syncthreads();
  #pragma unroll
  for (int i = 0; i < 4; ++i) {
    int e = tid + i * 256;
    int g = e >> 6;                           // 0..15 (ic group of 8)
    int pix = e & 63;                         // consecutive lanes -> pix
    uint4 v;
    v.x = tile[pix * 65 + g * 4 + 0];
    v.y = tile[pix * 65 + g * 4 + 1];
    v.z = tile[pix * 65 + g * 4 + 2];
    v.w = tile[pix * 65 + g * 4 + 3];
    *(uint4*)(xt + ((size_t)(n * 16 + g) * NPIX + hw0 + pix) * 8) = v;
  }
}

// MFMA quadrant: 4 m-frags x 2 n-frags x 2 k-steps = 16 MFMA.
#define QUAD(MH, NH)                                                          \
  do {                                                                        \
    __builtin_amdgcn_s_setprio(1);                                            \
    _Pragma("unroll") for (int mq = 0; mq < 4; ++mq)                          \
    _Pragma("unroll") for (int nf = 0; nf < 2; ++nf)                          \
    _Pragma("unroll") for (int kk = 0; kk < 2; ++kk)                          \
      acc[(MH)*4 + mq][(NH)*2 + nf] =                                         \
          __builtin_amdgcn_mfma_f32_16x16x32_f16(                             \
              af[mq][kk], bf[(NH)][nf][kk], acc[(MH)*4 + mq][(NH)*2 + nf],    \
              0, 0, 0);                                                       \
    __builtin_amdgcn_s_setprio(0);                                            \
  } while (0)

#define READB(BUFO, NH)                                                       \
  do {                                                                        \
    _Pragma("unroll") for (int nf = 0; nf < 2; ++nf)                          \
    _Pragma("unroll") for (int kk = 0; kk < 2; ++kk)                          \
      bf[(NH)][nf][kk] = *(const f16x8*)&lds[(BUFO) + 16384 + bhalf * 8192 +  \
          ((kk * 4 + lg) * 128 + bpl + (NH)*32 + nf * 16) * 8];               \
  } while (0)

__global__ __launch_bounds__(512, 2) void conv_mfma(
    const u16* __restrict__ Wt, const u16* __restrict__ xt,
    const float* __restrict__ bias, float* __restrict__ out,
    const u16* __restrict__ zp) {
  // LDS: [buf 2][ A: [half][k8][ocl][8] 32KB | B: [half][k8][pixl][8] 32KB ]
  __shared__ __align__(16) u16 lds[65536];    // 128 KB

  int tid  = threadIdx.x;                     // 0..511
  int lane = tid & 63;
  int wv   = tid >> 6;                        // 0..7
  int bid  = blockIdx.x;                      // 0..391
  int ptile = (bid & 7) * 49 + (bid >> 3);    // XCD swizzle (392 = 8*49)

  int wm = wv >> 2, wn = wv & 3;              // 2M x 4N waves
  int l15 = lane & 15, lg = lane >> 4;
  int bhalf = wn >> 1;
  int bpl = (wn & 1) * 64 + l15;

  // B staging: thread t owns granules (k8=tph, pixl) and (k8=tph+4, pixl).
  int pixl = tid & 127, tph = tid >> 7;       // tph 0..3
  int p0 = ptile * 256 + pixl, p1 = p0 + 128;
  int n0 = p0 / NPIX, r0 = p0 % NPIX, y0 = r0 / HW, x0 = r0 % HW;
  int n1 = p1 / NPIX, r1 = p1 % NPIX, y1 = r1 / HW, x1 = r1 % HW;
  // xt granule addr: ((n*16 + g) * NPIX + pix) * 16 bytes.
  const char* xtb = (const char*)xt;
  const char* wsrc = (const char*)Wt + tid * 16;
  const char* zpc = (const char*)zp;

  auto stageA = [&](int tn, int h) {
    const char* src = wsrc + (size_t)(tn * 2048 + h * 1024) * 16;
    u16* dst = &lds[(tn & 1) * 32768 + h * 8192 + tid * 8];
    gload16(src, dst);
    gload16(src + 8192, dst + 4096);
  };
  // B source for (tap, ich, pix-half h): granule (g = ich*8 + k8, rsh).
  auto bsrc = [&](int tap, int ich, int h) -> const char* {
    int t3 = tap / 3;
    int dh = t3 - 1, dw = (tap - t3 * 3) - 1;
    int y = (h ? y1 : y0) + dh, xx = (h ? x1 : x0) + dw;
    if ((unsigned)y >= HW || (unsigned)xx >= HW) return zpc;
    int n = h ? n1 : n0;
    int rsh = (h ? r1 : r0) + dh * HW + dw;
    return xtb + ((size_t)(n * 16 + ich * 8 + tph) * NPIX + rsh) * 16;
  };
  auto stageB = [&](int tn, int h, const char* src) {
    u16* dst = &lds[(tn & 1) * 32768 + 16384 + h * 8192 + tid * 8];
    gload16(src, dst);
    // second granule: k8 += 4 -> g += 4 -> + 4*NPIX*16 bytes (zp: stay).
    gload16(src == zpc ? zpc : src + (size_t)4 * NPIX * 16, dst + 4096);
  };

  f32x4 acc[8][4] = {};
  f16x8 af[4][2], bf[2][2][2];

  auto readA = [&](int bufo, int mh) {
    #pragma unroll
    for (int mq = 0; mq < 4; ++mq)
      #pragma unroll
      for (int kk = 0; kk < 2; ++kk)
        af[mq][kk] = *(const f16x8*)&lds[bufo + wm * 8192 +
            ((kk * 4 + lg) * 128 + mh * 64 + mq * 16 + l15) * 8];
  };

  // Prologue: stage K-tile 0 (8 loads/thread).
  stageA(0, 0); stageB(0, 0, bsrc(0, 0, 0));
  stageA(0, 1); stageB(0, 1, bsrc(0, 0, 1));

  for (int t = 0; t < NKT; ++t) {
    int bufo = (t & 1) * 32768;
    int tn = t + 1;
    const char *sb0 = zpc, *sb1 = zpc;
    if (tn < NKT) { sb0 = bsrc(tn >> 1, tn & 1, 0); sb1 = bsrc(tn >> 1, tn & 1, 1); }
    // ---- phase 0: quad (m0,n0); stage A0(t+1); the K-tile's only vmcnt.
    if (tn < NKT) { stageA(tn, 0); WAITVM2; } else { WAITVM0; }
    BARRIER;
    readA(bufo, 0); READB(bufo, 0);
    QUAD(0, 0);
    BARRIER;
    // ---- phase 1: quad (m0,n1); stage B0(t+1).
    READB(bufo, 1);
    if (tn < NKT) stageB(tn, 0, sb0);
    BARRIER;
    QUAD(0, 1);
    BARRIER;
    // ---- phase 2: quad (m1,n1); stage A1(t+1).
    readA(bufo, 1);
    if (tn < NKT) stageA(tn, 1);
    BARRIER;
    QUAD(1, 1);
    BARRIER;
    // ---- phase 3: quad (m1,n0); stage B1(t+1). B n0 frags still live.
    if (tn < NKT) stageB(tn, 1, sb1);
    BARRIER;
    QUAD(1, 0);
    BARRIER;
  }

  // Epilogue. C/D: row(oc) = lg*4 + reg, col(pix) = l15. nf4 innermost so
  // the four 64B chunks of each 256B region are consecutive stores.
  float* ob[4];
  #pragma unroll
  for (int nf4 = 0; nf4 < 4; ++nf4) {
    int p = ptile * 256 + wn * 64 + nf4 * 16 + l15;
    int n = p / NPIX, hw = p % NPIX;
    ob[nf4] = out + (size_t)n * COUT * NPIX + hw;
  }
  #pragma unroll
  for (int mi = 0; mi < 8; ++mi) {
    int oc = wm * 128 + mi * 16 + lg * 4;
    f32x4 bv = *(const f32x4*)&bias[oc];
    #pragma unroll
    for (int r = 0; r < 4; ++r) {
      size_t row = (size_t)(oc + r) * NPIX;
      #pragma unroll
      for (int nf4 = 0; nf4 < 4; ++nf4)
        ob[nf4][row] = acc[mi][nf4][r] + bv[r];
    }
  }
}

// ---- fallback (only if ws too small): naive fp32 direct conv
__global__ void conv_naive(const float* __restrict__ x, const float* __restrict__ W,
                           const float* __restrict__ b, float* __restrict__ out) {
  int idx = blockIdx.x * 256 + threadIdx.x;
  int hw = idx % NPIX;
  int tmp = idx / NPIX;
  int oc = tmp % COUT;
  int n = tmp / COUT;
  int h = hw / HW, w = hw % HW;
  float acc = b[oc];
  for (int ic = 0; ic < CIN; ++ic) {
    const float* xr = x + (size_t)(n * CIN + ic) * NPIX;
    const float* wr = W + (size_t)(oc * CIN + ic) * 9;
    #pragma unroll
    for (int kh = 0; kh < 3; ++kh) {
      int ih = h + kh - 1;
      if ((unsigned)ih >= HW) continue;
      #pragma unroll
      for (int kw = 0; kw < 3; ++kw) {
        int iw = w + kw - 1;
        if ((unsigned)iw >= HW) continue;
        acc += xr[ih * HW + iw] * wr[kh * 3 + kw];
      }
    }
  }
  out[idx] = acc;
}

extern "C" void kernel_launch(void* const* d_in, const int* in_sizes, int n_in,
                              void* d_out, int out_size, void* d_ws, size_t ws_size,
                              hipStream_t stream) {
  const float* x = (const float*)d_in[0];
  const float* W = (const float*)d_in[1];
  const float* b = (const float*)d_in[2];
  float* out = (float*)d_out;

  const size_t ZP_OFF = 0;                    // 256 B zero page
  const size_t WT_OFF = 256;                  // 294912 * 2 = 589824 B
  const size_t XT_OFF = 256 + 589824;
  const size_t NEED = XT_OFF + (size_t)TOTPIX * CIN * 2;  // ~26.3 MB

  if (ws_size < NEED) {
    conv_naive<<<TOTPIX * COUT / 256, 256, 0, stream>>>(x, W, b, out);
    return;
  }
  char* ws = (char*)d_ws;
  u16* zp = (u16*)(ws + ZP_OFF);
  u16* Wt = (u16*)(ws + WT_OFF);
  u16* xt = (u16*)(ws + XT_OFF);

  prep_w<<<1152, 256, 0, stream>>>(W, Wt, zp);
  prep_x<<<1568, 256, 0, stream>>>(x, xt);
  conv_mfma<<<392, 512, 0, stream>>>(Wt, xt, b, out, zp);
}